// Round 7
// baseline (8152.705 us; speedup 1.0000x reference)
//
#include <hip/hip_runtime.h>
#include <math.h>

#define BB 64
#define PP 196
#define SS 22
#define TT 21
#define VV 10000
#define EE 512
#define AA 512
#define UU 512
#define EC 2048
#define NBLK 512u

// d_out layout (floats): pred [B,T,V] | alpha [B,T,P] | seqs [B,S] | iter_lens [B] | order [B]
#define OUT_PRED  0
#define OUT_ALPHA (BB*TT*VV)
#define OUT_SEQ   (OUT_ALPHA + BB*TT*PP)
#define OUT_ILEN  (OUT_SEQ + BB*SS)
#define OUT_ORDER (OUT_ILEN + BB)

__device__ __forceinline__ float sigm(float x) { return 1.0f / (1.0f + expf(-x)); }

// ---------------------------------------------------------------------------
__global__ void k_sort(const int* __restrict__ lens, const int* __restrict__ seqs,
                       int* __restrict__ order, int* __restrict__ ilens,
                       float* __restrict__ out)
{
    __shared__ int ord_s[BB];
    int i = threadIdx.x;
    int li = lens[i];
    int rank = 0;
    for (int j = 0; j < BB; ++j) {
        int lj = lens[j];
        rank += (lj > li) || (lj == li && j < i);
    }
    ord_s[rank] = i;
    __syncthreads();
    int o = ord_s[i];
    order[i] = o;
    int il = lens[o] - 1;
    ilens[i] = il;
    for (int s = 0; s < SS; ++s)
        out[OUT_SEQ + i * SS + s] = (float)seqs[o * SS + s];
    out[OUT_ILEN + i] = (float)il;
    out[OUT_ORDER + i] = (float)o;
}

__global__ void k_rowoff(const int* __restrict__ order, const int* __restrict__ seqs,
                         int* __restrict__ roff1, int* __restrict__ roff2)
{
    int idx = blockIdx.x * 256 + threadIdx.x;
    if (idx < BB * PP) {
        int b = idx / PP, p = idx % PP;
        roff1[idx] = order[b] * (PP * EC) + p * EC;
    }
    if (idx < BB * TT) {
        int b = idx / TT, t = idx % TT;
        int tok = seqs[order[b] * SS + t];
        roff2[idx] = tok * EE;
    }
}

__global__ __launch_bounds__(256) void k_mean(const float* __restrict__ enc,
                                              const int* __restrict__ order,
                                              float* __restrict__ meanE)
{
    int idx = blockIdx.x * 256 + threadIdx.x;   // b*2048 + e
    int b = idx >> 11, e = idx & 2047;
    const float* base = enc + (size_t)order[b] * (PP * EC) + e;
    float s = 0.f;
    for (int p = 0; p < PP; ++p) s += base[p * EC];
    meanE[idx] = s * (1.0f / PP);
}

// ---------------------------------------------------------------------------
// fp32 tile GEMM, gathered A rows (setup only: att1, zemb). Unchanged.
__global__ __launch_bounds__(256) void k_gemm_tile(
    const float* __restrict__ Abase, const int* __restrict__ roff,
    const float* __restrict__ W, const float* __restrict__ bias,
    float* __restrict__ C, int M, int N, int K)
{
    __shared__ float As[16][128];
    __shared__ float Bs[16][128];
    int nwg = gridDim.x, bid = blockIdx.x;
    int q = nwg >> 3, r = nwg & 7;
    int x = bid & 7, y = bid >> 3;
    int lbid = (x < r ? x * (q + 1) : r * (q + 1) + (x - r) * q) + y;
    int ntn = N >> 7;
    int mt = lbid / ntn, nt = lbid % ntn;
    int tid = threadIdx.x;

    int arow = tid >> 1, akq = (tid & 1) * 8;
    int am = mt * 128 + arow; if (am > M - 1) am = M - 1;
    const float* aptr = Abase + (size_t)roff[am] + akq;
    int bkr = tid >> 5, bc4 = (tid & 31) * 4;
    const float* bptr = W + (size_t)bkr * N + nt * 128 + bc4;

    float4 a0 = *(const float4*)(aptr);
    float4 a1 = *(const float4*)(aptr + 4);
    float4 b0 = *(const float4*)(bptr);
    float4 b1 = *(const float4*)(bptr + (size_t)8 * N);

    int tr = tid >> 4, tc = tid & 15;
    float acc[8][8] = {};

    for (int k0 = 0; k0 < K; k0 += 16) {
        float* ac = &As[akq][arow];
        ac[0]   = a0.x; ac[128] = a0.y; ac[256] = a0.z; ac[384] = a0.w;
        ac[512] = a1.x; ac[640] = a1.y; ac[768] = a1.z; ac[896] = a1.w;
        *(float4*)&Bs[bkr][bc4] = b0;
        *(float4*)&Bs[bkr + 8][bc4] = b1;
        __syncthreads();
        if (k0 + 16 < K) {
            a0 = *(const float4*)(aptr + k0 + 16);
            a1 = *(const float4*)(aptr + k0 + 20);
            b0 = *(const float4*)(bptr + (size_t)(k0 + 16) * N);
            b1 = *(const float4*)(bptr + (size_t)(k0 + 24) * N);
        }
        #pragma unroll
        for (int kk = 0; kk < 16; ++kk) {
            float4 aL = *(float4*)&As[kk][tr * 4];
            float4 aH = *(float4*)&As[kk][tr * 4 + 64];
            float4 bL = *(float4*)&Bs[kk][tc * 4];
            float4 bH = *(float4*)&Bs[kk][tc * 4 + 64];
            float av[8] = {aL.x, aL.y, aL.z, aL.w, aH.x, aH.y, aH.z, aH.w};
            float bv[8] = {bL.x, bL.y, bL.z, bL.w, bH.x, bH.y, bH.z, bH.w};
            #pragma unroll
            for (int i = 0; i < 8; ++i)
                #pragma unroll
                for (int j = 0; j < 8; ++j)
                    acc[i][j] += av[i] * bv[j];
        }
        __syncthreads();
    }
    float4 bL = make_float4(0.f, 0.f, 0.f, 0.f), bH = bL;
    if (bias) {
        bL = *(const float4*)&bias[nt * 128 + tc * 4];
        bH = *(const float4*)&bias[nt * 128 + tc * 4 + 64];
    }
    #pragma unroll
    for (int ih = 0; ih < 2; ++ih)
        #pragma unroll
        for (int i2 = 0; i2 < 4; ++i2) {
            int i = ih * 4 + i2;
            int m = mt * 128 + ih * 64 + tr * 4 + i2;
            if (m < M) {
                float4 lo, hi;
                lo.x = acc[i][0] + bL.x; lo.y = acc[i][1] + bL.y;
                lo.z = acc[i][2] + bL.z; lo.w = acc[i][3] + bL.w;
                hi.x = acc[i][4] + bH.x; hi.y = acc[i][5] + bH.y;
                hi.z = acc[i][6] + bH.z; hi.w = acc[i][7] + bH.w;
                *(float4*)&C[(size_t)m * N + nt * 128 + tc * 4] = lo;
                *(float4*)&C[(size_t)m * N + nt * 128 + tc * 4 + 64] = hi;
            }
        }
}

// h = meanE@W_im + b_im ; c = meanE@W_ic + b_ic (z picks target). Setup-only.
__global__ __launch_bounds__(256) void k_initmc(
    const float* __restrict__ meanE, const float* __restrict__ Wim,
    const float* __restrict__ bim, const float* __restrict__ Wic,
    const float* __restrict__ bic, float* __restrict__ hB, float* __restrict__ cB)
{
    __shared__ float xs[16 * 512];
    int ry = blockIdx.y, ct = blockIdx.x;
    const float* W   = blockIdx.z ? Wic : Wim;
    const float* bia = blockIdx.z ? bic : bim;
    float* out       = blockIdx.z ? cB : hB;
    int ng = threadIdx.x & 31, rg = threadIdx.x >> 5;
    int col = ct * 128 + ng * 4;
    float acc[2][4] = {};
    for (int kc = 0; kc < 4; ++kc) {
        __syncthreads();
        for (int it = 0; it < 8; ++it) {
            int i4 = (it * 256 + threadIdx.x) * 4;
            int rr = i4 >> 9, k = i4 & 511;
            *(float4*)&xs[i4] =
                *(const float4*)&meanE[(size_t)(ry * 16 + rr) * EC + kc * 512 + k];
        }
        __syncthreads();
        const float* wp = W + (size_t)(kc * 512) * 512 + col;
        #pragma unroll 8
        for (int k = 0; k < 512; ++k) {
            float4 w = *(const float4*)(wp + (size_t)k * 512);
            float x0 = xs[(rg * 2) * 512 + k], x1 = xs[(rg * 2 + 1) * 512 + k];
            acc[0][0] += x0 * w.x; acc[0][1] += x0 * w.y; acc[0][2] += x0 * w.z; acc[0][3] += x0 * w.w;
            acc[1][0] += x1 * w.x; acc[1][1] += x1 * w.y; acc[1][2] += x1 * w.z; acc[1][3] += x1 * w.w;
        }
    }
    int r0 = ry * 16 + rg * 2;
    float4 bv = *(const float4*)&bia[col];
    float4 o0, o1;
    o0.x = acc[0][0] + bv.x; o0.y = acc[0][1] + bv.y; o0.z = acc[0][2] + bv.z; o0.w = acc[0][3] + bv.w;
    o1.x = acc[1][0] + bv.x; o1.y = acc[1][1] + bv.y; o1.z = acc[1][2] + bv.z; o1.w = acc[1][3] + bv.w;
    *(float4*)&out[(size_t)r0 * 512 + col] = o0;
    *(float4*)&out[(size_t)(r0 + 1) * 512 + col] = o1;
}

// ---------------------------------------------------------------------------
// Hand-rolled device-scope grid barrier (plain launch; no cooperative API).
// All NBLK blocks are co-resident by construction: LDS 33.8KB & VGPR<=256
// -> 2 blocks/CU x 256 CU = 512 slots. Bounded spin: a logic bug yields a
// wrong answer, not a hung container.
__device__ __forceinline__ void gridbar(unsigned* __restrict__ bar,
                                        unsigned* __restrict__ gen)
{
    __syncthreads();
    if (threadIdx.x == 0) {
        __threadfence();
        unsigned g = atomicAdd(gen, 0u);
        if (atomicAdd(bar, 1u) == NBLK - 1u) {
            atomicExch(bar, 0u);
            atomicAdd(gen, 1u);
        } else {
            unsigned spins = 0;
            while (atomicAdd(gen, 0u) == g && ++spins < (1u << 22))
                __builtin_amdgcn_s_sleep(1);
        }
        __threadfence();
    }
    __syncthreads();
}

// 64 rows x 128 cols x K=128 slice GEMM partial. x staged in LDS [64][132].
__device__ __forceinline__ void mm64p(
    float* __restrict__ xs,
    const float* __restrict__ x, int ldx, int kbase,
    const float* __restrict__ W, int ldw, int col0, int collim,
    float* __restrict__ dst, int ldd,
    int tcheck, const int* __restrict__ ilens)
{
    int tid = threadIdx.x;
    #pragma unroll
    for (int it = 0; it < 8; ++it) {
        int f4 = it * 256 + tid;
        int r = f4 >> 5, kf = (f4 & 31) * 4;
        *(float4*)&xs[r * 132 + kf] = *(const float4*)&x[(size_t)r * ldx + kbase + kf];
    }
    __syncthreads();
    int ng = tid & 31, rg = tid >> 5;
    int col = col0 + ng * 4;
    if (col + 4 <= collim) {
        float acc[8][4] = {};
        const float* wp = W + (size_t)kbase * ldw + col;
        #pragma unroll 4
        for (int k = 0; k < 128; ++k) {
            float4 w = *(const float4*)(wp + (size_t)k * ldw);
            #pragma unroll
            for (int i = 0; i < 8; ++i) {
                float xv = xs[(rg * 8 + i) * 132 + k];
                acc[i][0] += xv * w.x; acc[i][1] += xv * w.y;
                acc[i][2] += xv * w.z; acc[i][3] += xv * w.w;
            }
        }
        #pragma unroll
        for (int i = 0; i < 8; ++i) {
            int r = rg * 8 + i;
            if (tcheck < ilens[r])
                *(float4*)&dst[(size_t)r * ldd + col] = *(float4*)&acc[i][0];
        }
    }
    __syncthreads();
}

// att2/beta partials from c. b2 in [0,80): 20 ct x 4 kz.
__device__ __forceinline__ void ab_part(
    float* xs, int b2, const float* cB, const float* Wag, const float* Wb,
    float* att2P, float* betaP, int tcheck, const int* ilens)
{
    int ct = b2 >> 2, kz = b2 & 3;
    if (ct < 4)
        mm64p(xs, cB, 512, kz * 128, Wag, 512, ct * 128, 1 << 30,
              att2P + (size_t)kz * (BB * AA), 512, tcheck, ilens);
    else
        mm64p(xs, cB, 512, kz * 128, Wb, 2048, (ct - 4) * 128, 1 << 30,
              betaP + (size_t)kz * (BB * EC), 2048, tcheck, ilens);
}

// P1: e + softmax for one batch row (block-uniform return; 256 threads).
__device__ void score_part(
    float* smem, int b, const float* __restrict__ att1,
    const float* __restrict__ att2P, const float* __restrict__ bgen,
    const float* __restrict__ Wf, const int* __restrict__ ilens,
    float* __restrict__ alphaS, float* __restrict__ out, int t)
{
    if (t >= ilens[b]) return;
    float* att2g = smem;            // 512
    float* wfs   = smem + 512;      // 512
    float* es    = smem + 1024;     // 208
    float* red   = smem + 1232;     // 256
    int tid = threadIdx.x;
    for (int i = tid; i < AA; i += 256) {
        float s = bgen[i];
        #pragma unroll
        for (int kz = 0; kz < 4; ++kz) s += att2P[(size_t)kz * BB * AA + b * AA + i];
        att2g[i] = s;
        wfs[i] = Wf[i];
    }
    __syncthreads();
    int wv = tid >> 6, lane = tid & 63, a0 = lane * 8;
    float4 g0 = *(float4*)&att2g[a0], g1 = *(float4*)&att2g[a0 + 4];
    float4 w0 = *(float4*)&wfs[a0],  w1 = *(float4*)&wfs[a0 + 4];
    for (int p = wv; p < PP; p += 4) {
        const float4* A1 = (const float4*)(att1 + ((size_t)b * PP + p) * AA + a0);
        float4 x0 = A1[0], x1 = A1[1];
        float acc = fmaxf(x0.x + g0.x, 0.f) * w0.x + fmaxf(x0.y + g0.y, 0.f) * w0.y
                  + fmaxf(x0.z + g0.z, 0.f) * w0.z + fmaxf(x0.w + g0.w, 0.f) * w0.w
                  + fmaxf(x1.x + g1.x, 0.f) * w1.x + fmaxf(x1.y + g1.y, 0.f) * w1.y
                  + fmaxf(x1.z + g1.z, 0.f) * w1.z + fmaxf(x1.w + g1.w, 0.f) * w1.w;
        #pragma unroll
        for (int s = 32; s; s >>= 1) acc += __shfl_down(acc, s);
        if (lane == 0) es[p] = acc;
    }
    __syncthreads();
    float ev = (tid < PP) ? es[tid] : -1e30f;
    red[tid] = ev; __syncthreads();
    for (int s = 128; s >= 1; s >>= 1) {
        if (tid < s) red[tid] = fmaxf(red[tid], red[tid + s]);
        __syncthreads();
    }
    float mx = red[0]; __syncthreads();
    float ex = (tid < PP) ? expf(ev - mx) : 0.f;
    red[tid] = ex; __syncthreads();
    for (int s = 128; s >= 1; s >>= 1) {
        if (tid < s) red[tid] += red[tid + s];
        __syncthreads();
    }
    float inv = 1.0f / red[0];
    if (tid < PP) {
        float a = ex * inv;
        alphaS[b * PP + tid] = a;
        out[OUT_ALPHA + ((size_t)b * TT + t) * PP + tid] = a;
    }
}

// P2a: awe slice (512 e-values) for one row: bid -> b = bid>>2, chunk = bid&3.
__device__ void awe_part(
    float* smem, int bid, const float* __restrict__ alphaS,
    const float* __restrict__ enc, const int* __restrict__ order,
    const int* __restrict__ ilens, const float* __restrict__ betaP,
    const float* __restrict__ bbeta, float* __restrict__ aweB, int t)
{
    int b = bid >> 2, chunk = bid & 3;
    if (t >= ilens[b]) return;
    float* al = smem;   // 208
    int tid = threadIdx.x;
    if (tid < PP) al[tid] = alphaS[b * PP + tid];
    __syncthreads();
    int o = order[b];
    const float* ebase = enc + (size_t)o * PP * EC + chunk * 512;
    #pragma unroll
    for (int half = 0; half < 2; ++half) {
        int e = half * 256 + tid;
        float s = 0.f;
        #pragma unroll 4
        for (int p = 0; p < PP; ++p) s += al[p] * ebase[(size_t)p * EC + e];
        int eg = chunk * 512 + e;
        float br = bbeta[eg];
        #pragma unroll
        for (int kz = 0; kz < 4; ++kz)
            br += betaP[(size_t)kz * BB * EC + b * EC + eg];
        aweB[(size_t)b * EC + eg] = s * sigm(br);
    }
}

// P2b: vocab softmax for row b at step tp, from 4 logit partials (zlP region).
__device__ void pred_part(
    float* smem, int b, int tp, const float* __restrict__ logitP,
    const float* __restrict__ bout, const int* __restrict__ ilens,
    float* __restrict__ out)
{
    if (tp < 0 || tp >= ilens[b]) return;
    float* red = smem;   // 4 floats
    int tid = threadIdx.x, lane = tid & 63, wv = tid >> 6;
    const float* lb = logitP + (size_t)b * VV;
    float* po = out + OUT_PRED + ((size_t)b * TT + tp) * VV;
    float mx = -1e30f;
    for (int idx = tid; idx < VV; idx += 256) {
        float l = lb[idx] + lb[BB * VV + idx] + lb[2 * BB * VV + idx]
                + lb[3 * BB * VV + idx] + bout[idx];
        po[idx] = l;
        mx = fmaxf(mx, l);
    }
    #pragma unroll
    for (int s = 32; s; s >>= 1) mx = fmaxf(mx, __shfl_xor(mx, s));
    if (lane == 0) red[wv] = mx;
    __syncthreads();
    mx = fmaxf(fmaxf(red[0], red[1]), fmaxf(red[2], red[3]));
    __syncthreads();
    float sm = 0.f;
    for (int idx = tid; idx < VV; idx += 256) {
        float e = expf(po[idx] - mx);
        po[idx] = e;
        sm += e;
    }
    #pragma unroll
    for (int s = 32; s; s >>= 1) sm += __shfl_xor(sm, s);
    if (lane == 0) red[wv] = sm;
    __syncthreads();
    float inv = 1.0f / (red[0] + red[1] + red[2] + red[3]);
    for (int idx = tid; idx < VV; idx += 256) po[idx] *= inv;
}

// P4: LSTM gates from 16 awe-z partials + 4 h-z partials + zemb + bias.
__device__ __forceinline__ void gates_part(
    int bid, const float* __restrict__ zlP, const float* __restrict__ zhP,
    const float* __restrict__ zemb, const float* __restrict__ blstm,
    float* __restrict__ h, float* __restrict__ c,
    const int* __restrict__ ilens, int t)
{
    int idx = bid * 256 + threadIdx.x;   // b*512 + u
    int b = idx >> 9, u = idx & 511;
    if (t < ilens[b]) {
        const float* ze = zemb + ((size_t)b * TT + t) * EC;
        float g[4];
        #pragma unroll
        for (int j = 0; j < 4; ++j) {
            float s = ze[u + j * 512] + blstm[u + j * 512];
            #pragma unroll
            for (int kc = 0; kc < 16; ++kc)
                s += zlP[(size_t)kc * (BB * EC) + b * EC + u + j * 512];
            #pragma unroll
            for (int kc = 0; kc < 4; ++kc)
                s += zhP[(size_t)kc * (BB * EC) + b * EC + u + j * 512];
            g[j] = s;
        }
        float cold = c[idx];
        float cn = sigm(g[1]) * cold + sigm(g[0]) * tanhf(g[2]);
        float hn = sigm(g[3]) * tanhf(cn);
        c[idx] = cn; h[idx] = hn;
    }
}

// ---------------------------------------------------------------------------
// The whole 21-step recurrence in one plain-launched persistent kernel.
// 512 blocks x 256 threads; LDS 33.8KB, VGPR<=256 -> 2 blocks/CU guaranteed.
__global__ __launch_bounds__(256, 2) void k_megaloop(
    const float* __restrict__ att1, const float* __restrict__ enc,
    const int* __restrict__ order, const int* __restrict__ ilens,
    const float* __restrict__ bgen, const float* __restrict__ Wf,
    const float* __restrict__ bbeta, const float* __restrict__ Wag,
    const float* __restrict__ Wb, const float* __restrict__ Wo,
    const float* __restrict__ Wx2, const float* __restrict__ Wh,
    const float* __restrict__ zemb, const float* __restrict__ blstm,
    const float* __restrict__ bout, float* __restrict__ alphaS,
    float* __restrict__ att2P, float* __restrict__ betaP,
    float* __restrict__ aweB, float* __restrict__ hB, float* __restrict__ cB,
    float* __restrict__ zlP, float* __restrict__ zhP,
    unsigned* __restrict__ bar, unsigned* __restrict__ gen,
    float* __restrict__ out)
{
    __shared__ float smem[8448];   // 33,792 B: mm64p x-stage [64][132]
    int bid = blockIdx.x;

    // prologue: att2/beta(0) from c0 (80) + zh(0) from h0 (64, bids 80..143)
    if (bid < 80) {
        ab_part(smem, bid, cB, Wag, Wb, att2P, betaP, 0, ilens);
    } else if (bid < 144) {
        int b2 = bid - 80, ct = b2 >> 2, kz = b2 & 3;
        mm64p(smem, hB, 512, kz * 128, Wh, 2048, ct * 128, 1 << 30,
              zhP + (size_t)kz * (BB * EC), 2048, 0, ilens);
    }
    gridbar(bar, gen);

    for (int t = 0; t <= TT; ++t) {
        // P1: score(t) -> alphaS (64 blocks)
        if (t < TT) {
            if (bid < 64)
                score_part(smem, bid, att1, att2P, bgen, Wf, ilens, alphaS, out, t);
            gridbar(bar, gen);
        }
        // P2: awe(t) (256 blocks) | pred(t-1) (bids 256..319)
        if (bid < 256) {
            if (t < TT)
                awe_part(smem, bid, alphaS, enc, order, ilens, betaP, bbeta, aweB, t);
        } else if (bid < 320) {
            pred_part(smem, bid - 256, t - 1, zlP, bout, ilens, out);
        }
        if (t == TT) break;                 // uniform: all blocks exit together
        gridbar(bar, gen);

        // P3: z awe-partials (16 ct x 16 kz = 256 blocks) into zlP
        if (bid < 256) {
            int ct = bid >> 4, kz = bid & 15;
            mm64p(smem, aweB, 2048, kz * 128, Wx2, 2048, ct * 128, 1 << 30,
                  zlP + (size_t)kz * (BB * EC), 2048, t, ilens);
        }
        gridbar(bar, gen);

        // P4: gates (128 blocks) -> new h,c
        if (bid < 128) gates_part(bid, zlP, zhP, zemb, blstm, hB, cB, ilens, t);
        gridbar(bar, gen);

        // P5: logits(t) (316) | att2/beta(t+1) (80) | zh(t+1) (64)
        if (bid < 316) {
            int ct = bid >> 2, kz = bid & 3;
            mm64p(smem, cB, 512, kz * 128, Wo, VV, ct * 128, VV,
                  zlP + (size_t)kz * (BB * VV), VV, t, ilens);
        } else if (bid < 396) {
            if (t + 1 < TT)
                ab_part(smem, bid - 316, cB, Wag, Wb, att2P, betaP, t + 1, ilens);
        } else if (bid < 460) {
            int b2 = bid - 396, ct = b2 >> 2, kz = b2 & 3;
            mm64p(smem, hB, 512, kz * 128, Wh, 2048, ct * 128, 1 << 30,
                  zhP + (size_t)kz * (BB * EC), 2048, t + 1, ilens);
        }
        gridbar(bar, gen);
    }
}

// ---------------------------------------------------------------------------
extern "C" void kernel_launch(void* const* d_in, const int* in_sizes, int n_in,
                              void* d_out, int out_size, void* d_ws, size_t ws_size,
                              hipStream_t stream)
{
    (void)in_sizes; (void)n_in; (void)out_size; (void)ws_size;
    const float* enc  = (const float*)d_in[0];
    const int*   seqs = (const int*)d_in[1];
    const int*   lens = (const int*)d_in[2];
    const float* embT = (const float*)d_in[3];
    const float* W_ae = (const float*)d_in[4];
    const float* b_ae = (const float*)d_in[5];
    const float* W_ag = (const float*)d_in[6];
    const float* b_ag = (const float*)d_in[7];
    const float* W_af = (const float*)d_in[8];
    // d_in[9] = b_att_full: constant pre-softmax shift, cancels.
    const float* W_x  = (const float*)d_in[10];
    const float* W_h  = (const float*)d_in[11];
    const float* b_l  = (const float*)d_in[12];
    const float* W_im = (const float*)d_in[13];
    const float* b_im = (const float*)d_in[14];
    const float* W_ic = (const float*)d_in[15];
    const float* b_ic = (const float*)d_in[16];
    const float* W_b  = (const float*)d_in[17];
    const float* b_b  = (const float*)d_in[18];
    const float* W_o  = (const float*)d_in[19];
    const float* b_o  = (const float*)d_in[20];
    float* out = (float*)d_out;

    // ws layout (floats). zlP: z-partials (P3->P4) then logit partials
    // (P5->P2 next step) - disjoint lifetimes. meanE aliases att2P (dead
    // after k_initmc; att2P first written in megakernel prologue).
    float* ws     = (float*)d_ws;
    float* att1   = ws;                      // [B*P, A]            6,422,528
    float* zemb   = att1 + 6422528;          // [B*T, 4U]           2,752,512
    float* alphaS = zemb + 2752512;          // [B, P]                 12,544
    float* aweB   = alphaS + 12544;          // [B, ENC]              131,072
    float* att2P  = aweB + 131072;           // [4][B, A]             131,072 (= meanE)
    float* betaP  = att2P + 131072;          // [4][B, ENC]           524,288
    float* hB     = betaP + 524288;          // [B, U]                 32,768
    float* cB     = hB + 32768;              // [B, U]                 32,768
    float* zlP    = cB + 32768;              // max(16 zP, 4 logitP) 2,560,000
    float* zhP    = zlP + 2560000;           // [4][B, 4U]            524,288
    unsigned* bar = (unsigned*)(zhP + 524288);   // [64] barrier region
    unsigned* gen = bar + 32;                    // separate cache line
    int* order = (int*)(bar + 64);
    int* ilens = order + 64;
    int* roff1 = ilens + 64;                 // 12544
    int* roff2 = roff1 + 12544;              // 1344
    float* meanE = att2P;                    // alias

    // masked outputs default to 0; barrier counters start at 0
    hipMemsetAsync(out, 0, (size_t)OUT_SEQ * 4, stream);
    hipMemsetAsync(bar, 0, 256, stream);

    k_sort<<<1, 64, 0, stream>>>(lens, seqs, order, ilens, out);
    k_rowoff<<<49, 256, 0, stream>>>(order, seqs, roff1, roff2);
    k_mean<<<512, 256, 0, stream>>>(enc, order, meanE);
    k_initmc<<<dim3(4, 4, 2), 256, 0, stream>>>(meanE, W_im, b_im, W_ic, b_ic, hB, cB);

    // att1 = sorted_enc @ W_att_enc + b_att_enc   [12544 x 512], K=2048
    k_gemm_tile<<<98 * 4, 256, 0, stream>>>(enc, roff1, W_ae, b_ae, att1, 12544, 512, 2048);
    // zemb = emb(sorted tokens) @ W_x[0:512]      [1344 x 2048], K=512
    k_gemm_tile<<<11 * 16, 256, 0, stream>>>(embT, roff2, W_x, nullptr, zemb, 1344, 2048, 512);

    // the whole 21-step loop in one persistent kernel (plain launch)
    const float* Wx2 = W_x + (size_t)512 * 2048;
    k_megaloop<<<NBLK, 256, 0, stream>>>(
        att1, enc, order, ilens, b_ag, W_af, b_b, W_ag, W_b, W_o, Wx2, W_h,
        zemb, b_l, b_o, alphaS, att2P, betaP, aweB, hB, cB, zlP, zhP,
        bar, gen, out);
}

// Round 8
// 2677.818 us; speedup vs baseline: 3.0445x; 3.0445x over previous
//
#include <hip/hip_runtime.h>
#include <math.h>

#define BB 64
#define PP 196
#define SS 22
#define TT 21
#define VV 10000
#define EE 512
#define AA 512
#define UU 512
#define EC 2048

// d_out layout (floats): pred [B,T,V] | alpha [B,T,P] | seqs [B,S] | iter_lens [B] | order [B]
#define OUT_PRED  0
#define OUT_ALPHA (BB*TT*VV)
#define OUT_SEQ   (OUT_ALPHA + BB*TT*PP)
#define OUT_ILEN  (OUT_SEQ + BB*SS)
#define OUT_ORDER (OUT_ILEN + BB)

__device__ __forceinline__ float sigm(float x) { return 1.0f / (1.0f + expf(-x)); }

// ---------------------------------------------------------------------------
__global__ void k_sort(const int* __restrict__ lens, const int* __restrict__ seqs,
                       int* __restrict__ order, int* __restrict__ ilens,
                       float* __restrict__ out)
{
    __shared__ int ord_s[BB];
    int i = threadIdx.x;
    int li = lens[i];
    int rank = 0;
    for (int j = 0; j < BB; ++j) {
        int lj = lens[j];
        rank += (lj > li) || (lj == li && j < i);
    }
    ord_s[rank] = i;
    __syncthreads();
    int o = ord_s[i];
    order[i] = o;
    int il = lens[o] - 1;
    ilens[i] = il;
    for (int s = 0; s < SS; ++s)
        out[OUT_SEQ + i * SS + s] = (float)seqs[o * SS + s];
    out[OUT_ILEN + i] = (float)il;
    out[OUT_ORDER + i] = (float)o;
}

__global__ void k_rowoff(const int* __restrict__ order, const int* __restrict__ seqs,
                         int* __restrict__ roff1, int* __restrict__ roff2)
{
    int idx = blockIdx.x * 256 + threadIdx.x;
    if (idx < BB * PP) {
        int b = idx / PP, p = idx % PP;
        roff1[idx] = order[b] * (PP * EC) + p * EC;
    }
    if (idx < BB * TT) {
        int b = idx / TT, t = idx % TT;
        int tok = seqs[order[b] * SS + t];
        roff2[idx] = tok * EE;
    }
}

__global__ __launch_bounds__(256) void k_mean(const float* __restrict__ enc,
                                              const int* __restrict__ order,
                                              float* __restrict__ meanE)
{
    int idx = blockIdx.x * 256 + threadIdx.x;   // b*2048 + e
    int b = idx >> 11, e = idx & 2047;
    const float* base = enc + (size_t)order[b] * (PP * EC) + e;
    float s = 0.f;
    for (int p = 0; p < PP; ++p) s += base[p * EC];
    meanE[idx] = s * (1.0f / PP);
}

// ---------------------------------------------------------------------------
// fp32 tile GEMM, gathered A rows (setup only: att1, zemb).
// BM=64, BN=128, BK=16, 256 threads, 8x4 micro-tile, reg-prefetch,
// XCD-chunked swizzle. 12.8KB LDS -> ~3-4 blocks/CU at 784-block grid.
__global__ __launch_bounds__(256) void k_gemm_tile64(
    const float* __restrict__ Abase, const int* __restrict__ roff,
    const float* __restrict__ W, const float* __restrict__ bias,
    float* __restrict__ C, int M, int N, int K)
{
    __shared__ float As[16][72];    // [kk][row], pad 72 (2-way max on writes)
    __shared__ float Bs[16][128];
    int nwg = gridDim.x, bid = blockIdx.x;
    int q = nwg >> 3, r = nwg & 7;
    int x = bid & 7, y = bid >> 3;
    int lbid = (x < r ? x * (q + 1) : r * (q + 1) + (x - r) * q) + y;
    int ntn = N >> 7;
    int mt = lbid / ntn, nt = lbid % ntn;
    int tid = threadIdx.x;

    // A stage: 64 rows x 16 k; thread -> row = tid&63, k4 = (tid>>6)*4
    int arow = tid & 63, ak4 = (tid >> 6) * 4;
    int am = mt * 64 + arow; if (am > M - 1) am = M - 1;
    const float* aptr = Abase + (size_t)roff[am] + ak4;
    // B stage: 16 x 128; thread -> rows (tid>>5) and +8, col (tid&31)*4
    int bkr = tid >> 5, bc4 = (tid & 31) * 4;
    const float* bptr = W + (size_t)bkr * N + nt * 128 + bc4;

    float4 a0 = *(const float4*)(aptr);
    float4 b0 = *(const float4*)(bptr);
    float4 b1 = *(const float4*)(bptr + (size_t)8 * N);

    int tr = tid >> 5, tc = tid & 31;   // 8 row-groups x 32 col-groups
    float acc[8][4] = {};

    for (int k0 = 0; k0 < K; k0 += 16) {
        float* ac = &As[ak4][arow];
        ac[0] = a0.x; ac[72] = a0.y; ac[144] = a0.z; ac[216] = a0.w;
        *(float4*)&Bs[bkr][bc4] = b0;
        *(float4*)&Bs[bkr + 8][bc4] = b1;
        __syncthreads();
        if (k0 + 16 < K) {
            a0 = *(const float4*)(aptr + k0 + 16);
            b0 = *(const float4*)(bptr + (size_t)(k0 + 16) * N);
            b1 = *(const float4*)(bptr + (size_t)(k0 + 24) * N);
        }
        #pragma unroll
        for (int kk = 0; kk < 16; ++kk) {
            float4 aL = *(float4*)&As[kk][tr * 8];
            float4 aH = *(float4*)&As[kk][tr * 8 + 4];
            float4 bb = *(float4*)&Bs[kk][tc * 4];
            float av[8] = {aL.x, aL.y, aL.z, aL.w, aH.x, aH.y, aH.z, aH.w};
            #pragma unroll
            for (int i = 0; i < 8; ++i) {
                acc[i][0] += av[i] * bb.x; acc[i][1] += av[i] * bb.y;
                acc[i][2] += av[i] * bb.z; acc[i][3] += av[i] * bb.w;
            }
        }
        __syncthreads();
    }
    float4 bv = make_float4(0.f, 0.f, 0.f, 0.f);
    if (bias) bv = *(const float4*)&bias[nt * 128 + tc * 4];
    #pragma unroll
    for (int i = 0; i < 8; ++i) {
        int m = mt * 64 + tr * 8 + i;
        if (m < M) {
            float4 rr;
            rr.x = acc[i][0] + bv.x; rr.y = acc[i][1] + bv.y;
            rr.z = acc[i][2] + bv.z; rr.w = acc[i][3] + bv.w;
            *(float4*)&C[(size_t)m * N + nt * 128 + tc * 4] = rr;
        }
    }
}

// h = meanE@W_im + b_im ; c = meanE@W_ic + b_ic (z picks target). Setup-only.
__global__ __launch_bounds__(256) void k_initmc(
    const float* __restrict__ meanE, const float* __restrict__ Wim,
    const float* __restrict__ bim, const float* __restrict__ Wic,
    const float* __restrict__ bic, float* __restrict__ hB, float* __restrict__ cB)
{
    __shared__ float xs[16 * 512];
    int ry = blockIdx.y, ct = blockIdx.x;
    const float* W   = blockIdx.z ? Wic : Wim;
    const float* bia = blockIdx.z ? bic : bim;
    float* out       = blockIdx.z ? cB : hB;
    int ng = threadIdx.x & 31, rg = threadIdx.x >> 5;
    int col = ct * 128 + ng * 4;
    float acc[2][4] = {};
    for (int kc = 0; kc < 4; ++kc) {
        __syncthreads();
        for (int it = 0; it < 8; ++it) {
            int i4 = (it * 256 + threadIdx.x) * 4;
            int rr = i4 >> 9, k = i4 & 511;
            *(float4*)&xs[i4] =
                *(const float4*)&meanE[(size_t)(ry * 16 + rr) * EC + kc * 512 + k];
        }
        __syncthreads();
        const float* wp = W + (size_t)(kc * 512) * 512 + col;
        #pragma unroll 8
        for (int k = 0; k < 512; ++k) {
            float4 w = *(const float4*)(wp + (size_t)k * 512);
            float x0 = xs[(rg * 2) * 512 + k], x1 = xs[(rg * 2 + 1) * 512 + k];
            acc[0][0] += x0 * w.x; acc[0][1] += x0 * w.y; acc[0][2] += x0 * w.z; acc[0][3] += x0 * w.w;
            acc[1][0] += x1 * w.x; acc[1][1] += x1 * w.y; acc[1][2] += x1 * w.z; acc[1][3] += x1 * w.w;
        }
    }
    int r0 = ry * 16 + rg * 2;
    float4 bv = *(const float4*)&bia[col];
    float4 o0, o1;
    o0.x = acc[0][0] + bv.x; o0.y = acc[0][1] + bv.y; o0.z = acc[0][2] + bv.z; o0.w = acc[0][3] + bv.w;
    o1.x = acc[1][0] + bv.x; o1.y = acc[1][1] + bv.y; o1.z = acc[1][2] + bv.z; o1.w = acc[1][3] + bv.w;
    *(float4*)&out[(size_t)r0 * 512 + col] = o0;
    *(float4*)&out[(size_t)(r0 + 1) * 512 + col] = o1;
}

// ---------------------------------------------------------------------------
// Step-GEMM building block: one block = 64 batch rows x 128 cols x K=128
// slice, plain stores of partials, row-guarded by ilens.
__device__ __forceinline__ void mm64(
    float* __restrict__ xs,
    const float* __restrict__ x, int ldx, int kbase,
    const float* __restrict__ W, int ldw, int col0, int collim,
    float* __restrict__ dst, int ldd,
    int tcheck, const int* __restrict__ ilens)
{
    int tid = threadIdx.x;
    #pragma unroll
    for (int it = 0; it < 8; ++it) {
        int f4 = it * 256 + tid;
        int r = f4 >> 5, kf = (f4 & 31) * 4;
        *(float4*)&xs[r * 132 + kf] = *(const float4*)&x[(size_t)r * ldx + kbase + kf];
    }
    __syncthreads();
    int ng = tid & 31, rg = tid >> 5;
    int col = col0 + ng * 4;
    if (col + 4 > collim) return;
    float acc[8][4] = {};
    const float* wp = W + (size_t)kbase * ldw + col;
    #pragma unroll 4
    for (int k = 0; k < 128; ++k) {
        float4 w = *(const float4*)(wp + (size_t)k * ldw);
        #pragma unroll
        for (int i = 0; i < 8; ++i) {
            float xv = xs[(rg * 8 + i) * 132 + k];
            acc[i][0] += xv * w.x; acc[i][1] += xv * w.y;
            acc[i][2] += xv * w.z; acc[i][3] += xv * w.w;
        }
    }
    #pragma unroll
    for (int i = 0; i < 8; ++i) {
        int r = rg * 8 + i;
        if (tcheck < ilens[r])
            *(float4*)&dst[(size_t)r * ldd + col] = *(float4*)&acc[i][0];
    }
}

// att2/beta partials from c. b2 in [0,80): 20 ct x 4 kz.
__device__ __forceinline__ void ab_part(
    float* xs, int b2, const float* cB, const float* Wag, const float* Wb,
    float* att2P, float* betaP, int tcheck, const int* ilens)
{
    int ct = b2 >> 2, kz = b2 & 3;
    if (ct < 4)
        mm64(xs, cB, 512, kz * 128, Wag, 512, ct * 128, 1 << 30,
             att2P + (size_t)kz * (BB * AA), 512, tcheck, ilens);
    else
        mm64(xs, cB, 512, kz * 128, Wb, 2048, (ct - 4) * 128, 1 << 30,
             betaP + (size_t)kz * (BB * EC), 2048, tcheck, ilens);
}

// zh partials: h @ Wh (16 ct x 4 kz = 64 blocks).
__device__ __forceinline__ void zh_part(
    float* xs, int b2, const float* hB, const float* Wh,
    float* zhP, int tcheck, const int* ilens)
{
    int ct = b2 >> 2, kz = b2 & 3;
    mm64(xs, hB, 512, kz * 128, Wh, 2048, ct * 128, 1 << 30,
         zhP + (size_t)kz * (BB * EC), 2048, tcheck, ilens);
}

// prologue: att2/beta(0) from c0 (80 blocks) + zh(0) from h0 (64 blocks)
__global__ __launch_bounds__(256) void k_pre(
    const float* __restrict__ cB, const float* __restrict__ hB,
    const float* __restrict__ Wag, const float* __restrict__ Wb,
    const float* __restrict__ Wh, float* __restrict__ att2P,
    float* __restrict__ betaP, float* __restrict__ zhP,
    const int* __restrict__ ilens)
{
    __shared__ float xs[64 * 132];
    int bid = blockIdx.x;
    if (bid < 80) ab_part(xs, bid, cB, Wag, Wb, att2P, betaP, 0, ilens);
    else          zh_part(xs, bid - 80, hB, Wh, zhP, 0, ilens);
}

// K1: logits(t) [316] U att2beta(t+1) [80] U zh(t+1) [64]; all read new h,c.
__global__ __launch_bounds__(256) void k_fused1(
    const float* __restrict__ cB, const float* __restrict__ hB,
    const float* __restrict__ Wo, const float* __restrict__ Wag,
    const float* __restrict__ Wb, const float* __restrict__ Wh,
    float* __restrict__ logitP, float* __restrict__ att2P,
    float* __restrict__ betaP, float* __restrict__ zhP,
    const int* __restrict__ ilens, int t)
{
    __shared__ float xs[64 * 132];
    int bid = blockIdx.x;
    if (bid < 316) {
        int ct = bid >> 2, kz = bid & 3;      // 79 ct x 4 kz, K=128
        mm64(xs, cB, 512, kz * 128, Wo, VV, ct * 128, VV,
             logitP + (size_t)kz * (BB * VV), VV, t, ilens);
    } else if (bid < 396) {
        if (t + 1 < TT)
            ab_part(xs, bid - 316, cB, Wag, Wb, att2P, betaP, t + 1, ilens);
    } else {
        if (t + 1 < TT)
            zh_part(xs, bid - 396, hB, Wh, zhP, t + 1, ilens);
    }
}

// K3: z awe-partials (16 ct x 16 kz = 256 blocks) into zlP.
__global__ __launch_bounds__(256) void k_zg(
    const float* __restrict__ aweB, const float* __restrict__ Wx2,
    float* __restrict__ zlP, const int* __restrict__ ilens, int t)
{
    __shared__ float xs[64 * 132];
    int ct = blockIdx.x >> 4, kz = blockIdx.x & 15;
    mm64(xs, aweB, 2048, kz * 128, Wx2, 2048, ct * 128, 1 << 30,
         zlP + (size_t)kz * (BB * EC), 2048, t, ilens);
}

// ---------------------------------------------------------------------------
// K2: score(t) [blocks 0..63] U pred(t-1) [blocks 64..127], 512 threads.
__global__ __launch_bounds__(512) void k_scorepred(
    const float* __restrict__ att1, const float* __restrict__ att2P,
    const float* __restrict__ bgen, const float* __restrict__ Wf,
    const float* __restrict__ logitP, const float* __restrict__ bout,
    const int* __restrict__ ilens, float* __restrict__ alphaS,
    float* __restrict__ out, int t)
{
    int tid = threadIdx.x;
    if (blockIdx.x < 64) {
        // ---- score ----
        int b = blockIdx.x;
        if (t >= TT || t >= ilens[b]) return;
        __shared__ float att2g[AA], wfs[AA], es[PP], red[512];
        att2g[tid] = att2P[b * AA + tid] + att2P[BB * AA + b * AA + tid]
                   + att2P[2 * BB * AA + b * AA + tid] + att2P[3 * BB * AA + b * AA + tid]
                   + bgen[tid];
        wfs[tid] = Wf[tid];
        __syncthreads();
        int wv = tid >> 6, lane = tid & 63;
        int a0 = lane * 8;
        float4 g0 = *(float4*)&att2g[a0], g1 = *(float4*)&att2g[a0 + 4];
        float4 w0 = *(float4*)&wfs[a0],  w1 = *(float4*)&wfs[a0 + 4];
        for (int p = wv; p < PP; p += 8) {
            const float4* A1 = (const float4*)(att1 + ((size_t)b * PP + p) * AA + a0);
            float4 x0 = A1[0], x1 = A1[1];
            float acc = fmaxf(x0.x + g0.x, 0.f) * w0.x + fmaxf(x0.y + g0.y, 0.f) * w0.y
                      + fmaxf(x0.z + g0.z, 0.f) * w0.z + fmaxf(x0.w + g0.w, 0.f) * w0.w
                      + fmaxf(x1.x + g1.x, 0.f) * w1.x + fmaxf(x1.y + g1.y, 0.f) * w1.y
                      + fmaxf(x1.z + g1.z, 0.f) * w1.z + fmaxf(x1.w + g1.w, 0.f) * w1.w;
            #pragma unroll
            for (int s = 32; s; s >>= 1) acc += __shfl_down(acc, s);
            if (lane == 0) es[p] = acc;
        }
        __syncthreads();
        float ev = (tid < PP) ? es[tid] : -1e30f;
        red[tid] = ev; __syncthreads();
        for (int s = 256; s >= 1; s >>= 1) {
            if (tid < s) red[tid] = fmaxf(red[tid], red[tid + s]);
            __syncthreads();
        }
        float mx = red[0]; __syncthreads();
        float ex = (tid < PP) ? expf(ev - mx) : 0.f;
        red[tid] = ex; __syncthreads();
        for (int s = 256; s >= 1; s >>= 1) {
            if (tid < s) red[tid] += red[tid + s];
            __syncthreads();
        }
        float inv = 1.0f / red[0];
        if (tid < PP) {
            float al = ex * inv;
            alphaS[b * PP + tid] = al;
            out[OUT_ALPHA + ((size_t)b * TT + t) * PP + tid] = al;
        }
    } else {
        // ---- pred for step t-1 ----
        int b = blockIdx.x - 64;
        int tp = t - 1;
        if (tp < 0 || tp >= ilens[b]) return;
        __shared__ float red8[8];
        int lane = tid & 63, wv = tid >> 6;
        const float* lb = logitP + (size_t)b * VV;
        float v[20];
        #pragma unroll
        for (int i = 0; i < 20; ++i) {
            int idx = tid + i * 512;
            if (idx < VV) {
                v[i] = lb[idx] + lb[BB * VV + idx] + lb[2 * BB * VV + idx]
                     + lb[3 * BB * VV + idx] + bout[idx];
            } else v[i] = -1e30f;
        }
        float mx = v[0];
        #pragma unroll
        for (int i = 1; i < 20; ++i) mx = fmaxf(mx, v[i]);
        #pragma unroll
        for (int s = 32; s; s >>= 1) mx = fmaxf(mx, __shfl_xor(mx, s));
        if (lane == 0) red8[wv] = mx;
        __syncthreads();
        if (tid == 0) {
            float m2 = red8[0];
            for (int i = 1; i < 8; ++i) m2 = fmaxf(m2, red8[i]);
            red8[0] = m2;
        }
        __syncthreads();
        mx = red8[0];
        __syncthreads();
        float sm = 0.f;
        #pragma unroll
        for (int i = 0; i < 20; ++i) {
            int idx = tid + i * 512;
            float e = (idx < VV) ? expf(v[i] - mx) : 0.f;
            v[i] = e; sm += e;
        }
        #pragma unroll
        for (int s = 32; s; s >>= 1) sm += __shfl_xor(sm, s);
        if (lane == 0) red8[wv] = sm;
        __syncthreads();
        if (tid == 0) {
            float s2 = 0.f;
            for (int i = 0; i < 8; ++i) s2 += red8[i];
            red8[0] = s2;
        }
        __syncthreads();
        float inv = 1.0f / red8[0];
        float* po = out + OUT_PRED + ((size_t)b * TT + tp) * VV;
        #pragma unroll
        for (int i = 0; i < 20; ++i) {
            int idx = tid + i * 512;
            if (idx < VV) po[idx] = v[i] * inv;
        }
    }
}

// awe = (alpha . enc) * sigmoid(sum betaP + b_b)
__global__ __launch_bounds__(256) void k_awe(
    const float* __restrict__ alphaS, const float* __restrict__ enc,
    const int* __restrict__ order, const int* __restrict__ ilens,
    const float* __restrict__ betaP, const float* __restrict__ bbeta,
    float* __restrict__ awe, int t)
{
    int b = blockIdx.y;
    if (t >= ilens[b]) return;
    int chunk = blockIdx.x, tid = threadIdx.x;
    __shared__ float al[PP];
    if (tid < PP) al[tid] = alphaS[b * PP + tid];
    __syncthreads();
    int e = chunk * 256 + tid;
    const float* ebase = enc + (size_t)order[b] * (PP * EC) + e;
    float s = 0.f;
    #pragma unroll 4
    for (int p = 0; p < PP; ++p) s += al[p] * ebase[(size_t)p * EC];
    float br = bbeta[e] + betaP[b * EC + e] + betaP[BB * EC + b * EC + e]
             + betaP[2 * BB * EC + b * EC + e] + betaP[3 * BB * EC + b * EC + e];
    awe[b * EC + e] = s * sigm(br);
}

// LSTM gates from 16 awe-z partials + 4 h-z partials + zemb + bias.
__global__ __launch_bounds__(256) void k_gates(
    const float* __restrict__ zlP, const float* __restrict__ zhP,
    const float* __restrict__ zemb, const float* __restrict__ blstm,
    float* __restrict__ h, float* __restrict__ c,
    const int* __restrict__ ilens, int t)
{
    int idx = blockIdx.x * 256 + threadIdx.x;   // b*512 + u
    int b = idx >> 9, u = idx & 511;
    if (t >= ilens[b]) return;
    const float* ze = zemb + ((size_t)b * TT + t) * EC;
    float g[4];
    #pragma unroll
    for (int j = 0; j < 4; ++j) {
        float s = ze[u + j * 512] + blstm[u + j * 512];
        #pragma unroll
        for (int kc = 0; kc < 16; ++kc)
            s += zlP[(size_t)kc * (BB * EC) + b * EC + u + j * 512];
        #pragma unroll
        for (int kc = 0; kc < 4; ++kc)
            s += zhP[(size_t)kc * (BB * EC) + b * EC + u + j * 512];
        g[j] = s;
    }
    float cold = c[idx];
    float cn = sigm(g[1]) * cold + sigm(g[0]) * tanhf(g[2]);
    float hn = sigm(g[3]) * tanhf(cn);
    c[idx] = cn; h[idx] = hn;
}

// ---------------------------------------------------------------------------
extern "C" void kernel_launch(void* const* d_in, const int* in_sizes, int n_in,
                              void* d_out, int out_size, void* d_ws, size_t ws_size,
                              hipStream_t stream)
{
    (void)in_sizes; (void)n_in; (void)out_size; (void)ws_size;
    const float* enc  = (const float*)d_in[0];
    const int*   seqs = (const int*)d_in[1];
    const int*   lens = (const int*)d_in[2];
    const float* embT = (const float*)d_in[3];
    const float* W_ae = (const float*)d_in[4];
    const float* b_ae = (const float*)d_in[5];
    const float* W_ag = (const float*)d_in[6];
    const float* b_ag = (const float*)d_in[7];
    const float* W_af = (const float*)d_in[8];
    // d_in[9] = b_att_full: constant pre-softmax shift, cancels.
    const float* W_x  = (const float*)d_in[10];
    const float* W_h  = (const float*)d_in[11];
    const float* b_l  = (const float*)d_in[12];
    const float* W_im = (const float*)d_in[13];
    const float* b_im = (const float*)d_in[14];
    const float* W_ic = (const float*)d_in[15];
    const float* b_ic = (const float*)d_in[16];
    const float* W_b  = (const float*)d_in[17];
    const float* b_b  = (const float*)d_in[18];
    const float* W_o  = (const float*)d_in[19];
    const float* b_o  = (const float*)d_in[20];
    float* out = (float*)d_out;

    // ws layout (floats). zlP: z awe-partials (zg->gates) then logit
    // partials (fused1->scorepred next step) - disjoint lifetimes.
    // meanE aliases att2P (dead after k_initmc; att2P written by k_pre).
    float* ws     = (float*)d_ws;
    float* att1   = ws;                      // [B*P, A]            6,422,528
    float* zemb   = att1 + 6422528;          // [B*T, 4U]           2,752,512
    float* alphaS = zemb + 2752512;          // [B, P]                 12,544
    float* aweB   = alphaS + 12544;          // [B, ENC]              131,072
    float* att2P  = aweB + 131072;           // [4][B, A]             131,072 (= meanE)
    float* betaP  = att2P + 131072;          // [4][B, ENC]           524,288
    float* hB     = betaP + 524288;          // [B, U]                 32,768
    float* cB     = hB + 32768;              // [B, U]                 32,768
    float* zlP    = cB + 32768;              // max(16 zP, 4 logitP) 2,560,000
    float* zhP    = zlP + 2560000;           // [4][B, 4U]            524,288
    int* order = (int*)(zhP + 524288);
    int* ilens = order + 64;
    int* roff1 = ilens + 64;                 // 12544
    int* roff2 = roff1 + 12544;              // 1344
    float* meanE  = att2P;                   // alias
    float* logitP = zlP;                     // alias

    // masked outputs default to 0 (inactive rows never written)
    hipMemsetAsync(out, 0, (size_t)OUT_SEQ * 4, stream);

    k_sort<<<1, 64, 0, stream>>>(lens, seqs, order, ilens, out);
    k_rowoff<<<49, 256, 0, stream>>>(order, seqs, roff1, roff2);
    k_mean<<<512, 256, 0, stream>>>(enc, order, meanE);
    k_initmc<<<dim3(4, 4, 2), 256, 0, stream>>>(meanE, W_im, b_im, W_ic, b_ic, hB, cB);

    // att1 = sorted_enc @ W_att_enc + b_att_enc   [12544 x 512], K=2048
    k_gemm_tile64<<<196 * 4, 256, 0, stream>>>(enc, roff1, W_ae, b_ae, att1, 12544, 512, 2048);
    // zemb = emb(sorted tokens) @ W_x[0:512]      [1344 x 2048], K=512
    k_gemm_tile64<<<21 * 16, 256, 0, stream>>>(embT, roff2, W_x, nullptr, zemb, 1344, 2048, 512);

    // att2/beta(0) + zh(0)
    k_pre<<<144, 256, 0, stream>>>(cB, hB, W_ag, W_b, W_h, att2P, betaP, zhP, ilens);

    const float* Wx2 = W_x + (size_t)512 * 2048;
    for (int t = 0; t < TT; ++t) {
        k_scorepred<<<128, 512, 0, stream>>>(
            att1, att2P, b_ag, W_af, logitP, b_o, ilens, alphaS, out, t);
        k_awe<<<dim3(8, 64), 256, 0, stream>>>(
            alphaS, enc, order, ilens, betaP, b_b, aweB, t);
        k_zg<<<256, 256, 0, stream>>>(aweB, Wx2, zlP, ilens, t);
        k_gates<<<128, 256, 0, stream>>>(zlP, zhP, zemb, b_l, hB, cB, ilens, t);
        k_fused1<<<460, 256, 0, stream>>>(
            cB, hB, W_o, W_ag, W_b, W_h, logitP, att2P, betaP, zhP, ilens, t);
    }
    // final pred (t=20); score part self-disables at t=TT
    k_scorepred<<<128, 512, 0, stream>>>(
        att1, att2P, b_ag, W_af, logitP, b_o, ilens, alphaS, out, TT);
}